// Round 5
// baseline (115.378 us; speedup 1.0000x reference)
//
#include <hip/hip_runtime.h>

// LSTM: B=65536 seqs, T=256, E=H=5, x in {0,1}.
// TWO lanes per sequence (gate-type split) -> 2048 waves = 2 waves/SIMD so
// co-wave issue hides the trans-latency stalls (~30% of wall at occ=1).
// Trans lane-ops are conserved: even lane computes gates {i0..4, g0..4},
// odd lane {f0..4, o0..4} -> 10 exp2/lane/step, perfectly balanced.
// Combine ownership: even lane -> cell units {0,1,2}; odd -> {3,4} (+1 dummy
// slot). Cross-lane exchange via DPP quad_perm[1,0,3,2] (full-rate v_mov).
// Per-lane weight gather at setup makes the step body role-uniform.
// Trans per wave-step: 10 gate exp2 + 3 Ec exp2 + 2 triple-rcp = 15.
//   sigmoid(v)=rcp(1+exp2(-v*log2e)), tanh via (Ec-1)/(Ec+1); scales folded
//   into weights; c kept pre-scaled (chat=2log2e*c).

typedef float v2f __attribute__((ext_vector_type(2)));

constexpr int TT = 256;
constexpr int HH = 5;

__device__ __forceinline__ float fexp2(float v) { return __builtin_amdgcn_exp2f(v); }
__device__ __forceinline__ float frcp(float v)  { return __builtin_amdgcn_rcpf(v); }
// swap value with the neighbor lane (lane ^ 1) via DPP quad_perm [1,0,3,2]
__device__ __forceinline__ float pswap(float v) {
    return __builtin_bit_cast(float, __builtin_amdgcn_mov_dpp(
        __builtin_bit_cast(int, v), 0xB1, 0xF, 0xF, true));
}

__global__ __launch_bounds__(256)
__attribute__((amdgpu_waves_per_eu(2, 2)))
void lstm_split(
    const int* __restrict__ x,       // [B, T]
    const float* __restrict__ emb,   // [2, E]
    const float* __restrict__ W_ih,  // [4H, E]
    const float* __restrict__ W_hh,  // [4H, H]
    const float* __restrict__ b_ih,  // [4H]
    const float* __restrict__ b_hh,  // [4H]
    const float* __restrict__ W_lin, // [2, H]
    const float* __restrict__ b_lin, // [2]
    float* __restrict__ out)         // [B, 2]
{
    const int t   = blockIdx.x * blockDim.x + threadIdx.x;
    const int seq = t >> 1;
    const bool r1 = (t & 1);          // role: 0 = {i,g}+units012, 1 = {f,o}+units34

    const float NL2E  = -1.4426950408889634f;  // -log2(e)   (sigmoid rows)
    const float T2L2E =  2.8853900817779268f;  // 2*log2(e)  (tanh rows)

    // pair j -> rows (A = sigmoid-type row, B = A+10):
    //   role0: A-rows {0,1,2,8,9}   (i0,i1,i2,f3,f4), B = {g0,g1,g2,o3,o4}
    //   role1: A-rows {3,4,5,6,7}   (i3,i4,f0,f1,f2), B = {g3,g4,o0,o1,o2}
    // h-position k -> unit: role0 [0,1,2,3,4]; role1 [3,4,0,1,2]
    v2f wpk[HH][5], basepk[5], deltapk[5];
#pragma unroll
    for (int j = 0; j < 5; ++j) {
        const int rA = r1 ? (3 + j) : (j < 3 ? j : j + 5);
        const int rB = rA + 10;
        const float sA = NL2E;
        const float sB = (rB < 15) ? T2L2E : NL2E;   // g rows vs o rows
        float a0 = b_ih[rA] + b_hh[rA], a1 = a0;
        float c0 = b_ih[rB] + b_hh[rB], c1 = c0;
#pragma unroll
        for (int e = 0; e < 5; ++e) {
            a0 = fmaf(W_ih[rA * 5 + e], emb[e],     a0);
            a1 = fmaf(W_ih[rA * 5 + e], emb[5 + e], a1);
            c0 = fmaf(W_ih[rB * 5 + e], emb[e],     c0);
            c1 = fmaf(W_ih[rB * 5 + e], emb[5 + e], c1);
        }
        basepk[j][0]  = sA * a0;        basepk[j][1]  = sB * c0;
        deltapk[j][0] = sA * (a1 - a0); deltapk[j][1] = sB * (c1 - c0);
#pragma unroll
        for (int k = 0; k < 5; ++k) {
            const int u = r1 ? (k < 2 ? 3 + k : k - 2) : k;   // unit at position k
            wpk[k][j][0] = sA * W_hh[rA * 5 + u];
            wpk[k][j][1] = sB * W_hh[rB * 5 + u];
        }
    }

    float hm[HH]  = {0.f, 0.f, 0.f, 0.f, 0.f};  // h in lane-position order
    float chat[3] = {0.f, 0.f, 0.f};            // owned scaled cells (+dummy)

    auto step = [&](int xt) {
        const float xtf = (float)xt;
        v2f xv; xv[0] = xtf; xv[1] = xtf;
        v2f g[5];
#pragma unroll
        for (int j = 0; j < 5; ++j)
            g[j] = __builtin_elementwise_fma(xv, deltapk[j], basepk[j]);
#pragma unroll
        for (int k = 0; k < 5; ++k) {
            v2f hv; hv[0] = hm[k]; hv[1] = hm[k];
#pragma unroll
            for (int j = 0; j < 5; ++j)
                g[j] = __builtin_elementwise_fma(wpk[k][j], hv, g[j]);
        }
        float EA[5], EB[5];
#pragma unroll
        for (int j = 0; j < 5; ++j) { EA[j] = fexp2(g[j][0]); EB[j] = fexp2(g[j][1]); }

        // ---- exchange Ef (A-side): role0 recv {Ef0,Ef1,Ef2}; role1 {Ef3,Ef4,.} ----
        float RFs[3];
        RFs[0] = pswap(r1 ? EA[2] : EA[3]);
        RFs[1] = pswap(r1 ? EA[3] : EA[4]);
        RFs[2] = pswap(EA[4]);

        // ---- c-combine slots: unit = role0 s / role1 3+s (s=2 dummy) ----
        float N[3], D[3];
#pragma unroll
        for (int s = 0; s < 3; ++s) {
            float Ei = EA[s], Eg = EB[s], Ef = RFs[s];
            float Ai = 1.f + Ei, Af = 1.f + Ef, Ag = 1.f + Eg;
            float P  = Ai * Ag;
            D[s] = P * Af;
            float tt = fmaf(T2L2E, Eg, -T2L2E);      // 2log2e*(Eg-1)
            N[s] = fmaf(chat[s], P, tt * Af);
        }
        {   // one rcp for all three: chat_s = N_s / D_s
            float P01 = D[0] * D[1];
            float R   = frcp(P01 * D[2]);
            float q01 = D[2] * R;                    // 1/(D0*D1)
            chat[0] = (N[0] * D[1]) * q01;
            chat[1] = (N[1] * D[0]) * q01;
            chat[2] = (N[2] * P01) * R;
        }
        // keep the dummy slot (role1 s=2) finite; no-op for real chats (|.|<~15)
        chat[2] = fminf(fmaxf(chat[2], -40.f), 40.f);

        // ---- exchange Eo (B-side): role0 recv {Eo0,Eo1,Eo2}; role1 {Eo3,Eo4,.} ----
        float ROs[3];
        ROs[0] = pswap(r1 ? EB[2] : EB[3]);
        ROs[1] = pswap(r1 ? EB[3] : EB[4]);
        ROs[2] = pswap(EB[4]);

        // ---- h slots: h = (Ec-1)/((1+Eo)(1+Ec)) ----
        float Tn[3], Dn[3];
#pragma unroll
        for (int s = 0; s < 3; ++s) {
            float Ec = fexp2(chat[s]);
            Dn[s] = (1.f + ROs[s]) * (1.f + Ec);
            Tn[s] = Ec - 1.f;
        }
        float hs[3];
        {
            float P01 = Dn[0] * Dn[1];
            float R   = frcp(P01 * Dn[2]);
            float q01 = Dn[2] * R;
            hs[0] = (Tn[0] * Dn[1]) * q01;
            hs[1] = (Tn[1] * Dn[0]) * q01;
            hs[2] = (Tn[2] * P01) * R;
        }
        // ---- h exchange + position-ordered assembly ----
        float ra = pswap(hs[0]);
        float rb = pswap(hs[1]);
        float rc = pswap(hs[2]);
        hm[0] = hs[0];
        hm[1] = hs[1];
        hm[2] = r1 ? ra : hs[2];
        hm[3] = r1 ? rb : ra;
        hm[4] = r1 ? rc : rb;
    };

    // ---- main scan: 64 int4 loads, prefetch-next, 4 steps per iter ----
    const int4* xr = reinterpret_cast<const int4*>(x + (size_t)seq * TT);
    int4 cur = xr[0];
#pragma unroll 1
    for (int it = 0; it < TT / 4 - 1; ++it) {
        int4 nxt = xr[it + 1];
        step(cur.x); step(cur.y); step(cur.z); step(cur.w);
        cur = nxt;
    }
    step(cur.x); step(cur.y); step(cur.z); step(cur.w);

    // ---- linear head (even lane holds h in natural order) ----
    if (!r1) {
        float o0 = b_lin[0], o1 = b_lin[1];
#pragma unroll
        for (int j = 0; j < 5; ++j) {
            o0 = fmaf(W_lin[j],     hm[j], o0);
            o1 = fmaf(W_lin[5 + j], hm[j], o1);
        }
        reinterpret_cast<float2*>(out)[seq] = make_float2(o0, o1);
    }
}

extern "C" void kernel_launch(void* const* d_in, const int* in_sizes, int n_in,
                              void* d_out, int out_size, void* d_ws, size_t ws_size,
                              hipStream_t stream) {
    const int* x        = (const int*)d_in[0];
    const float* emb    = (const float*)d_in[1];
    const float* W_ih   = (const float*)d_in[2];
    const float* W_hh   = (const float*)d_in[3];
    const float* b_ih   = (const float*)d_in[4];
    const float* b_hh   = (const float*)d_in[5];
    const float* W_lin  = (const float*)d_in[6];
    const float* b_lin  = (const float*)d_in[7];
    float* out          = (float*)d_out;

    const int B = in_sizes[0] / TT;     // 65536
    const int threads = 2 * B;          // 2 lanes per sequence
    const int block = 256;
    const int grid = threads / block;   // 512 blocks -> 2048 waves -> 2/SIMD

    lstm_split<<<grid, block, 0, stream>>>(x, emb, W_ih, W_hh, b_ih, b_hh,
                                           W_lin, b_lin, out);
}

// Round 6
// 93.722 us; speedup vs baseline: 1.2311x; 1.2311x over previous
//
#include <hip/hip_runtime.h>

// LSTM: B=65536 seqs, T=256, E=H=5, x in {0,1}. One thread per sequence.
// 1024 waves = 1 wave/SIMD structurally. Issue-cycle model (validated R3/R5):
// trans ops (v_exp/v_rcp) block issue ~16 cyc at wave64; full-rate VALU 2 cyc.
// R3: 25 exp2 + 6 rcp = 496 cyc + ~306 full-rate + ~340 stalls = 1144.
// R6: (a) v2f unit-pair packing of BOTH combine phases (v_pk_* ops) cuts
//     full-rate to ~230 cyc; (b) all 20 gate exp2 issued as one batch
//     (o-gate hoisted out of the h-phase dependency zone).
// Math (exact, fp32): sigmoid/tanh share denominators:
//   c' = [chat*Ai*Ag + 2log2e*(Eg-1)*Af]/(Ai*Af*Ag),  A* = 1+E*
//   h  = sigma(o)*tanh(c') = (Ec-1)/((1+Eo)(1+Ec))
// rcps pair-grouped (rcp(Da*Db) serves two units; |D|^2 <= ~2^92 < 2^127).
// c kept pre-scaled (chat = 2log2e*c) so Ec = exp2(chat) directly.
//
// Gate-pair layout (pair p, half h -> weight row):
//   p0..7: row = (p>>1)*5 + (p&1)*2 + h   -> (i0,i1)(i2,i3)(f0,f1)(f2,f3)
//                                            (g0,g1)(g2,g3)(o0,o1)(o2,o3)
//   p8: (i4,f4) = rows {4,9};  p9: (g4,o4) = rows {14,19}
// so exp2(g[p]) lands directly in combine-ready unit-pair shape.

typedef float v2f __attribute__((ext_vector_type(2)));

constexpr int TT = 256;

__device__ __forceinline__ float fexp2(float v) { return __builtin_amdgcn_exp2f(v); }
__device__ __forceinline__ float frcp(float v)  { return __builtin_amdgcn_rcpf(v); }

__device__ __forceinline__ int pair_row(int p, int h) {
    if (p < 8) return (p >> 1) * 5 + (p & 1) * 2 + h;
    return (p == 8) ? (h ? 9 : 4) : (h ? 19 : 14);
}

__global__ __launch_bounds__(256, 1) void lstm_fused(
    const int* __restrict__ x,       // [B, T]
    const float* __restrict__ emb,   // [2, E]
    const float* __restrict__ W_ih,  // [4H, E]
    const float* __restrict__ W_hh,  // [4H, H]
    const float* __restrict__ b_ih,  // [4H]
    const float* __restrict__ b_hh,  // [4H]
    const float* __restrict__ W_lin, // [2, H]
    const float* __restrict__ b_lin, // [2]
    float* __restrict__ out)         // [B, 2]
{
    const int b = blockIdx.x * blockDim.x + threadIdx.x;

    const float NL2E  = -1.4426950408889634f;  // -log2(e)   (sigmoid rows)
    const float T2L2E =  2.8853900817779268f;  // 2*log2(e)  (tanh rows)
    const v2f ONE = {1.f, 1.f};
    const v2f T2v = {T2L2E, T2L2E};

    // ---- setup: scaled base/delta/W per pair, pinned to v-regs ----
    v2f bpk[10], dpk[10];     // gate bias (x=0) and x-delta, pre-scaled
    v2f wpk[5][10];           // wpk[k][p][h] = s(row)*W_hh[row*5+k]
#pragma unroll
    for (int p = 0; p < 10; ++p) {
        float v0[2], v1[2];
#pragma unroll
        for (int h = 0; h < 2; ++h) {
            const int r = pair_row(p, h);
            const float s = (r >= 10 && r < 15) ? T2L2E : NL2E;
            float g0 = b_ih[r] + b_hh[r], g1 = g0;
#pragma unroll
            for (int e = 0; e < 5; ++e) {
                float w = W_ih[r * 5 + e];
                g0 = fmaf(w, emb[e],     g0);
                g1 = fmaf(w, emb[5 + e], g1);
            }
            v0[h] = s * g0;
            v1[h] = s * (g1 - g0);
#pragma unroll
            for (int k = 0; k < 5; ++k) {
                float w = s * W_hh[r * 5 + k];
                asm volatile("" : "+v"(w));
                wpk[k][p][h] = w;
            }
        }
        asm volatile("" : "+v"(v0[0]), "+v"(v0[1]), "+v"(v1[0]), "+v"(v1[1]));
        bpk[p][0] = v0[0]; bpk[p][1] = v0[1];
        dpk[p][0] = v1[0]; dpk[p][1] = v1[1];
    }

    v2f chat01 = {0.f, 0.f}, chat23 = {0.f, 0.f};
    float chat4 = 0.f;
    v2f h01 = {0.f, 0.f}, h23 = {0.f, 0.f};
    float h4 = 0.f;

    auto step = [&](int xt) {
        const float xtf = (float)xt;
        v2f xv; xv[0] = xtf; xv[1] = xtf;
        v2f g[10];
#pragma unroll
        for (int p = 0; p < 10; ++p)
            g[p] = __builtin_elementwise_fma(xv, dpk[p], bpk[p]);
        // ---- recurrent matvec: 5 broadcast h's x 10 pairs ----
        const float hk[5] = {h01[0], h01[1], h23[0], h23[1], h4};
#pragma unroll
        for (int k = 0; k < 5; ++k) {
            v2f hv; hv[0] = hk[k]; hv[1] = hk[k];
#pragma unroll
            for (int p = 0; p < 10; ++p)
                g[p] = __builtin_elementwise_fma(wpk[k][p], hv, g[p]);
        }
        // ---- all 20 gate exp2 in one batch ----
        v2f E[10];
#pragma unroll
        for (int p = 0; p < 10; ++p) {
            E[p][0] = fexp2(g[p][0]);
            E[p][1] = fexp2(g[p][1]);
        }
        // E[0]=Ei01 E[1]=Ei23 E[2]=Ef01 E[3]=Ef23 E[4]=Eg01 E[5]=Eg23
        // E[6]=Eo01 E[7]=Eo23 E[8]=(Ei4,Ef4) E[9]=(Eg4,Eo4)

        // ---- c-phase (unit-pair packed) ----
        v2f Ai01 = E[0] + ONE, Af01 = E[2] + ONE, Ag01 = E[4] + ONE;
        v2f P01 = Ai01 * Ag01, D01 = P01 * Af01;
        v2f t01 = __builtin_elementwise_fma(T2v, E[4], -T2v);
        v2f N01 = __builtin_elementwise_fma(chat01, P01, t01 * Af01);

        v2f Ai23 = E[1] + ONE, Af23 = E[3] + ONE, Ag23 = E[5] + ONE;
        v2f P23 = Ai23 * Ag23, D23 = P23 * Af23;
        v2f t23 = __builtin_elementwise_fma(T2v, E[5], -T2v);
        v2f N23 = __builtin_elementwise_fma(chat23, P23, t23 * Af23);

        v2f AiAf4 = E[8] + ONE;   // (Ai4, Af4)
        v2f AgAo4 = E[9] + ONE;   // (Ag4, Ao4)
        float P4 = AiAf4[0] * AgAo4[0];
        float D4 = P4 * AiAf4[1];
        float t4 = fmaf(T2L2E, E[9][0], -T2L2E);
        float N4 = fmaf(chat4, P4, t4 * AiAf4[1]);

        {   // paired reciprocals: chat = N/D via rcp(D0*D1)
            float R01 = frcp(D01[0] * D01[1]);
            v2f Rv01; Rv01[0] = R01; Rv01[1] = R01;
            chat01 = (N01 * __builtin_shufflevector(D01, D01, 1, 0)) * Rv01;
            float R23 = frcp(D23[0] * D23[1]);
            v2f Rv23; Rv23[0] = R23; Rv23[1] = R23;
            chat23 = (N23 * __builtin_shufflevector(D23, D23, 1, 0)) * Rv23;
            chat4 = N4 * frcp(D4);
        }

        // ---- h-phase: h = (Ec-1)/((1+Eo)(1+Ec)) ----
        v2f Ec01; Ec01[0] = fexp2(chat01[0]); Ec01[1] = fexp2(chat01[1]);
        v2f Ec23; Ec23[0] = fexp2(chat23[0]); Ec23[1] = fexp2(chat23[1]);
        float Ec4 = fexp2(chat4);

        v2f Dn01 = (E[6] + ONE) * (Ec01 + ONE), Tn01 = Ec01 - ONE;
        v2f Dn23 = (E[7] + ONE) * (Ec23 + ONE), Tn23 = Ec23 - ONE;
        float Dn4 = AgAo4[1] * (Ec4 + 1.f), Tn4 = Ec4 - 1.f;

        {
            float R01 = frcp(Dn01[0] * Dn01[1]);
            v2f Rv01; Rv01[0] = R01; Rv01[1] = R01;
            h01 = (Tn01 * __builtin_shufflevector(Dn01, Dn01, 1, 0)) * Rv01;
            float R23 = frcp(Dn23[0] * Dn23[1]);
            v2f Rv23; Rv23[0] = R23; Rv23[1] = R23;
            h23 = (Tn23 * __builtin_shufflevector(Dn23, Dn23, 1, 0)) * Rv23;
            h4 = Tn4 * frcp(Dn4);
        }
    };

    // ---- main scan: 64 int4 loads, prefetch-next, 4 steps per iter ----
    const int4* xr = reinterpret_cast<const int4*>(x + (size_t)b * TT);
    int4 cur = xr[0];
#pragma unroll 1
    for (int it = 0; it < TT / 4 - 1; ++it) {
        int4 nxt = xr[it + 1];
        step(cur.x); step(cur.y); step(cur.z); step(cur.w);
        cur = nxt;
    }
    step(cur.x); step(cur.y); step(cur.z); step(cur.w);

    // ---- linear head ----
    const float hfin[5] = {h01[0], h01[1], h23[0], h23[1], h4};
    float o0 = b_lin[0], o1 = b_lin[1];
#pragma unroll
    for (int j = 0; j < 5; ++j) {
        o0 = fmaf(W_lin[j],     hfin[j], o0);
        o1 = fmaf(W_lin[5 + j], hfin[j], o1);
    }
    reinterpret_cast<float2*>(out)[b] = make_float2(o0, o1);
}

extern "C" void kernel_launch(void* const* d_in, const int* in_sizes, int n_in,
                              void* d_out, int out_size, void* d_ws, size_t ws_size,
                              hipStream_t stream) {
    const int* x        = (const int*)d_in[0];
    const float* emb    = (const float*)d_in[1];
    const float* W_ih   = (const float*)d_in[2];
    const float* W_hh   = (const float*)d_in[3];
    const float* b_ih   = (const float*)d_in[4];
    const float* b_hh   = (const float*)d_in[5];
    const float* W_lin  = (const float*)d_in[6];
    const float* b_lin  = (const float*)d_in[7];
    float* out          = (float*)d_out;

    const int B = in_sizes[0] / TT;   // 65536
    const int block = 256;
    const int grid = B / block;       // 256 blocks -> 1024 waves -> 1/SIMD

    lstm_fused<<<grid, block, 0, stream>>>(x, emb, W_ih, W_hh, b_ih, b_hh,
                                           W_lin, b_lin, out);
}

// Round 7
// 93.170 us; speedup vs baseline: 1.2384x; 1.0059x over previous
//
#include <hip/hip_runtime.h>

// LSTM: B=65536 seqs, T=256, E=H=5, x in {0,1}. One thread per sequence.
// 1024 waves = 1 wave/SIMD. Issue model (validated R3/R5/R6):
//   full-rate VALU 2 cyc, v_exp/v_rcp 16 cyc at wave64.
//   R6: busy 712 (230 full + 31 trans*16) + 418 stall = 1130 cyc/step.
// R7: weight set (wave-uniform) moved to SGPR pairs -- v_pk_fma_f32 takes a
//     64-bit scalar operand s[2n:2n+1], so matvec weights k=0..3 live as
//     uniform doubles (80 SGPRs) at zero extra instructions. VGPR demand
//     drops ~80 regs -> scheduler can overlap the independent unit-strands
//     (pair01/pair23/unit4) across trans-latency tails.
//     o-gate exp2s hand-placed in the c-phase rcp shadow.
// Math identical to R6 (absmax 4.9e-4):
//   c' = [chat*Ai*Ag + 2log2e*(Eg-1)*Af]/(Ai*Af*Ag),  A* = 1+E*
//   h  = (Ec-1)/((1+Eo)(1+Ec));  chat = 2log2e*c;  rcp pair-grouped.
// Gate-pair layout: p0..7: row=(p>>1)*5+(p&1)*2+h ->
//   (i0,i1)(i2,i3)(f0,f1)(f2,f3)(g0,g1)(g2,g3)(o0,o1)(o2,o3)
//   p8:(i4,f4)=rows{4,9}; p9:(g4,o4)=rows{14,19}

typedef float v2f __attribute__((ext_vector_type(2)));

constexpr int TT = 256;

__device__ __forceinline__ float fexp2(float v) { return __builtin_amdgcn_exp2f(v); }
__device__ __forceinline__ float frcp(float v)  { return __builtin_amdgcn_rcpf(v); }

__device__ __forceinline__ int pair_row(int p, int h) {
    if (p < 8) return (p >> 1) * 5 + (p & 1) * 2 + h;
    return (p == 8) ? (h ? 9 : 4) : (h ? 19 : 14);
}

// pack two uniform floats into a uniform 64-bit value (SGPR pair residency)
__device__ __forceinline__ double upack(float w0, float w1) {
    unsigned lo = (unsigned)__builtin_amdgcn_readfirstlane(__builtin_bit_cast(int, w0));
    unsigned hi = (unsigned)__builtin_amdgcn_readfirstlane(__builtin_bit_cast(int, w1));
    unsigned long long u = ((unsigned long long)hi << 32) | lo;
    return __builtin_bit_cast(double, u);
}

__global__ __launch_bounds__(256)
__attribute__((amdgpu_waves_per_eu(1, 1)))
void lstm_fused(
    const int* __restrict__ x,       // [B, T]
    const float* __restrict__ emb,   // [2, E]
    const float* __restrict__ W_ih,  // [4H, E]
    const float* __restrict__ W_hh,  // [4H, H]
    const float* __restrict__ b_ih,  // [4H]
    const float* __restrict__ b_hh,  // [4H]
    const float* __restrict__ W_lin, // [2, H]
    const float* __restrict__ b_lin, // [2]
    float* __restrict__ out)         // [B, 2]
{
    const int b = blockIdx.x * blockDim.x + threadIdx.x;

    const float NL2E  = -1.4426950408889634f;  // -log2(e)   (sigmoid rows)
    const float T2L2E =  2.8853900817779268f;  // 2*log2(e)  (tanh rows)
    const v2f ONE = {1.f, 1.f};
    const v2f T2v = {T2L2E, T2L2E};

    // ---- setup ----
    double wu[4][10];   // matvec weights k=0..3, uniform -> SGPR pairs
    v2f    wv[10];      // matvec weights k=4, pinned VGPR
    v2f bpk[10], dpk[10];
#pragma unroll
    for (int p = 0; p < 10; ++p) {
        float v0[2], v1[2], w4[2];
        float wk[4][2];
#pragma unroll
        for (int h = 0; h < 2; ++h) {
            const int r = pair_row(p, h);
            const float s = (r >= 10 && r < 15) ? T2L2E : NL2E;
            float g0 = b_ih[r] + b_hh[r], g1 = g0;
#pragma unroll
            for (int e = 0; e < 5; ++e) {
                float w = W_ih[r * 5 + e];
                g0 = fmaf(w, emb[e],     g0);
                g1 = fmaf(w, emb[5 + e], g1);
            }
            v0[h] = s * g0;
            v1[h] = s * (g1 - g0);
#pragma unroll
            for (int k = 0; k < 4; ++k) wk[k][h] = s * W_hh[r * 5 + k];
            w4[h] = s * W_hh[r * 5 + 4];
        }
#pragma unroll
        for (int k = 0; k < 4; ++k) wu[k][p] = upack(wk[k][0], wk[k][1]);
        asm volatile("" : "+v"(w4[0]), "+v"(w4[1]));
        wv[p][0] = w4[0]; wv[p][1] = w4[1];
        asm volatile("" : "+v"(v0[0]), "+v"(v0[1]), "+v"(v1[0]), "+v"(v1[1]));
        bpk[p][0] = v0[0]; bpk[p][1] = v0[1];
        dpk[p][0] = v1[0]; dpk[p][1] = v1[1];
    }

    v2f chat01 = {0.f, 0.f}, chat23 = {0.f, 0.f};
    float chat4 = 0.f;
    v2f h01 = {0.f, 0.f}, h23 = {0.f, 0.f};
    float h4 = 0.f;

    auto step = [&](int xt) {
        const float xtf = (float)xt;
        v2f xv; xv[0] = xtf; xv[1] = xtf;
        v2f g[10];
#pragma unroll
        for (int p = 0; p < 10; ++p)
            g[p] = __builtin_elementwise_fma(xv, dpk[p], bpk[p]);
        // ---- recurrent matvec: k=0..3 from SGPR pairs, k=4 from VGPR ----
        const float hk[4] = {h01[0], h01[1], h23[0], h23[1]};
#pragma unroll
        for (int k = 0; k < 4; ++k) {
            v2f hv; hv[0] = hk[k]; hv[1] = hk[k];
#pragma unroll
            for (int p = 0; p < 10; ++p) {
                v2f w = __builtin_bit_cast(v2f, wu[k][p]);
                g[p] = __builtin_elementwise_fma(w, hv, g[p]);
            }
        }
        {
            v2f hv; hv[0] = h4; hv[1] = h4;
#pragma unroll
            for (int p = 0; p < 10; ++p)
                g[p] = __builtin_elementwise_fma(wv[p], hv, g[p]);
        }

        // ---- c-phase inputs first: i,f,g gates + unit4 pairs (16 exp2) ----
        v2f E0, E1, E2, E3, E4, E5, E8, E9;
        E0[0] = fexp2(g[0][0]); E0[1] = fexp2(g[0][1]);   // Ei01
        E1[0] = fexp2(g[1][0]); E1[1] = fexp2(g[1][1]);   // Ei23
        E2[0] = fexp2(g[2][0]); E2[1] = fexp2(g[2][1]);   // Ef01
        E3[0] = fexp2(g[3][0]); E3[1] = fexp2(g[3][1]);   // Ef23
        E4[0] = fexp2(g[4][0]); E4[1] = fexp2(g[4][1]);   // Eg01
        E5[0] = fexp2(g[5][0]); E5[1] = fexp2(g[5][1]);   // Eg23
        E8[0] = fexp2(g[8][0]); E8[1] = fexp2(g[8][1]);   // (Ei4,Ef4)
        E9[0] = fexp2(g[9][0]); E9[1] = fexp2(g[9][1]);   // (Eg4,Eo4)

        // ---- c-combine ----
        v2f Ai01 = E0 + ONE, Af01 = E2 + ONE, Ag01 = E4 + ONE;
        v2f P01 = Ai01 * Ag01, D01 = P01 * Af01;
        v2f t01 = __builtin_elementwise_fma(T2v, E4, -T2v);
        v2f N01 = __builtin_elementwise_fma(chat01, P01, t01 * Af01);

        v2f Ai23 = E1 + ONE, Af23 = E3 + ONE, Ag23 = E5 + ONE;
        v2f P23 = Ai23 * Ag23, D23 = P23 * Af23;
        v2f t23 = __builtin_elementwise_fma(T2v, E5, -T2v);
        v2f N23 = __builtin_elementwise_fma(chat23, P23, t23 * Af23);

        v2f AiAf4 = E8 + ONE;   // (Ai4, Af4)
        v2f AgAo4 = E9 + ONE;   // (Ag4, Ao4)
        float P4 = AiAf4[0] * AgAo4[0];
        float D4 = P4 * AiAf4[1];
        float t4 = fmaf(T2L2E, E9[0], -T2L2E);
        float N4 = fmaf(chat4, P4, t4 * AiAf4[1]);

        // ---- o-gate exp2 issued into the c-rcp shadow ----
        float R01 = frcp(D01[0] * D01[1]);
        float R23 = frcp(D23[0] * D23[1]);
        float R4g = frcp(D4);
        v2f E6, E7;
        E6[0] = fexp2(g[6][0]); E6[1] = fexp2(g[6][1]);   // Eo01
        E7[0] = fexp2(g[7][0]); E7[1] = fexp2(g[7][1]);   // Eo23
        {
            v2f Rv01; Rv01[0] = R01; Rv01[1] = R01;
            chat01 = (N01 * __builtin_shufflevector(D01, D01, 1, 0)) * Rv01;
            v2f Rv23; Rv23[0] = R23; Rv23[1] = R23;
            chat23 = (N23 * __builtin_shufflevector(D23, D23, 1, 0)) * Rv23;
            chat4 = N4 * R4g;
        }

        // ---- h-phase: h = (Ec-1)/((1+Eo)(1+Ec)) ----
        v2f Ec01; Ec01[0] = fexp2(chat01[0]); Ec01[1] = fexp2(chat01[1]);
        v2f Ec23; Ec23[0] = fexp2(chat23[0]); Ec23[1] = fexp2(chat23[1]);
        float Ec4 = fexp2(chat4);

        v2f Dn01 = (E6 + ONE) * (Ec01 + ONE), Tn01 = Ec01 - ONE;
        v2f Dn23 = (E7 + ONE) * (Ec23 + ONE), Tn23 = Ec23 - ONE;
        float Dn4 = AgAo4[1] * (Ec4 + 1.f), Tn4 = Ec4 - 1.f;

        {
            float S01 = frcp(Dn01[0] * Dn01[1]);
            v2f Sv01; Sv01[0] = S01; Sv01[1] = S01;
            h01 = (Tn01 * __builtin_shufflevector(Dn01, Dn01, 1, 0)) * Sv01;
            float S23 = frcp(Dn23[0] * Dn23[1]);
            v2f Sv23; Sv23[0] = S23; Sv23[1] = S23;
            h23 = (Tn23 * __builtin_shufflevector(Dn23, Dn23, 1, 0)) * Sv23;
            h4 = Tn4 * frcp(Dn4);
        }
    };

    // ---- main scan: 64 int4 loads, prefetch-next, 4 steps per iter ----
    const int4* xr = reinterpret_cast<const int4*>(x + (size_t)b * TT);
    int4 cur = xr[0];
#pragma unroll 1
    for (int it = 0; it < TT / 4 - 1; ++it) {
        int4 nxt = xr[it + 1];
        step(cur.x); step(cur.y); step(cur.z); step(cur.w);
        cur = nxt;
    }
    step(cur.x); step(cur.y); step(cur.z); step(cur.w);

    // ---- linear head ----
    const float hfin[5] = {h01[0], h01[1], h23[0], h23[1], h4};
    float o0 = b_lin[0], o1 = b_lin[1];
#pragma unroll
    for (int j = 0; j < 5; ++j) {
        o0 = fmaf(W_lin[j],     hfin[j], o0);
        o1 = fmaf(W_lin[5 + j], hfin[j], o1);
    }
    reinterpret_cast<float2*>(out)[b] = make_float2(o0, o1);
}

extern "C" void kernel_launch(void* const* d_in, const int* in_sizes, int n_in,
                              void* d_out, int out_size, void* d_ws, size_t ws_size,
                              hipStream_t stream) {
    const int* x        = (const int*)d_in[0];
    const float* emb    = (const float*)d_in[1];
    const float* W_ih   = (const float*)d_in[2];
    const float* W_hh   = (const float*)d_in[3];
    const float* b_ih   = (const float*)d_in[4];
    const float* b_hh   = (const float*)d_in[5];
    const float* W_lin  = (const float*)d_in[6];
    const float* b_lin  = (const float*)d_in[7];
    float* out          = (float*)d_out;

    const int B = in_sizes[0] / TT;   // 65536
    const int block = 256;
    const int grid = B / block;       // 256 blocks -> 1024 waves -> 1/SIMD

    lstm_fused<<<grid, block, 0, stream>>>(x, emb, W_ih, W_hh, b_ih, b_hh,
                                           W_lin, b_lin, out);
}